// Round 1
// baseline (413.116 us; speedup 1.0000x reference)
//
#include <hip/hip_runtime.h>

constexpr int B  = 16;
constexpr int H  = 128;
constexpr int CL = 2048;
constexpr int QL = 256;
constexpr int SPLITC = 4;
constexpr float NEG = -1e30f;

__device__ __forceinline__ float neginf() { return -__builtin_inff(); }

// ---------------- K1: bias terms cterm[b,c], qterm[b,q] ----------------
__global__ __launch_bounds__(256) void k1_bias(
    const float* __restrict__ ctx, const float* __restrict__ qry,
    const float* __restrict__ w,
    float* __restrict__ cterm, float* __restrict__ qterm) {
  int idx = blockIdx.x * 256 + threadIdx.x;
  if (idx < B * CL) {
    int b = idx / CL, c = idx % CL;
    const float* p = ctx + (size_t)b * H * CL + c;
    float acc = 0.f;
    #pragma unroll 8
    for (int h = 0; h < H; ++h) acc = fmaf(p[(size_t)h * CL], w[H + h], acc);
    cterm[idx] = acc;
  } else if (idx < B * CL + B * QL) {
    int i2 = idx - B * CL;
    int b = i2 / QL, q = i2 % QL;
    const float* p = qry + (size_t)b * H * QL + q;
    float acc = 0.f;
    #pragma unroll 8
    for (int h = 0; h < H; ++h) acc = fmaf(p[h * QL], w[h], acc);
    qterm[i2] = acc;
  }
}

// ---------------- K2: s[b,c,q] = cterm + qterm + (ctx*wcq)^T @ qry ----------------
// grid (QL/64, CL/64, B), block 256. 64x64 tile, 4x4 per thread, K=H chunked by 32.
__global__ __launch_bounds__(256) void k2_score(
    const float* __restrict__ ctx, const float* __restrict__ qry,
    const float* __restrict__ w, const float* __restrict__ cterm,
    const float* __restrict__ qterm, float* __restrict__ s_out) {
  __shared__ float As[32][64];  // As[kk][cc] = ctx[b,h0+kk,c0+cc]*wcq[h0+kk]
  __shared__ float Bs[32][64];  // Bs[kk][qq] = qry[b,h0+kk,q0+qq]
  const int b  = blockIdx.z;
  const int c0 = blockIdx.y * 64;
  const int q0 = blockIdx.x * 64;
  const int tid = threadIdx.x;
  const int tx = tid & 15, ty = tid >> 4;
  const float* ctxb = ctx + (size_t)b * H * CL;
  const float* qryb = qry + (size_t)b * H * QL;
  float acc[4][4] = {};
  for (int h0 = 0; h0 < H; h0 += 32) {
    #pragma unroll
    for (int i = 0; i < 8; ++i) {
      int lin = i * 256 + tid;
      int kk = lin >> 6, cc = lin & 63;
      As[kk][cc] = ctxb[(size_t)(h0 + kk) * CL + c0 + cc] * w[2 * H + h0 + kk];
      Bs[kk][cc] = qryb[(h0 + kk) * QL + q0 + cc];
    }
    __syncthreads();
    #pragma unroll
    for (int kk = 0; kk < 32; ++kk) {
      float a[4], bq[4];
      #pragma unroll
      for (int i = 0; i < 4; ++i) a[i] = As[kk][ty * 4 + i];
      #pragma unroll
      for (int j = 0; j < 4; ++j) bq[j] = Bs[kk][tx * 4 + j];
      #pragma unroll
      for (int i = 0; i < 4; ++i)
        #pragma unroll
        for (int j = 0; j < 4; ++j) acc[i][j] = fmaf(a[i], bq[j], acc[i][j]);
    }
    __syncthreads();
  }
  float qt[4];
  #pragma unroll
  for (int j = 0; j < 4; ++j) qt[j] = qterm[b * QL + q0 + tx * 4 + j];
  #pragma unroll
  for (int i = 0; i < 4; ++i) {
    int c = c0 + ty * 4 + i;
    float ct = cterm[b * CL + c];
    float4 v;
    v.x = acc[i][0] + ct + qt[0];
    v.y = acc[i][1] + ct + qt[1];
    v.z = acc[i][2] + ct + qt[2];
    v.w = acc[i][3] + ct + qt[3];
    *(float4*)&s_out[((size_t)b * CL + c) * QL + q0 + tx * 4] = v;
  }
}

// ---------------- K3: row softmax stats over q (axis 2) ----------------
// one wave per row (b,c); block=256 -> 4 rows/block
__global__ __launch_bounds__(256) void k3_rowstats(
    const float* __restrict__ s, const int* __restrict__ qmask,
    float* __restrict__ rmax, float* __restrict__ rinv) {
  int row = blockIdx.x * 4 + (threadIdx.x >> 6);  // b*CL + c
  int lane = threadIdx.x & 63;
  int b = row / CL;
  const float* sp = s + (size_t)row * QL;
  float4 v = *(const float4*)&sp[lane * 4];
  int4 m4 = *(const int4*)&qmask[b * QL + lane * 4];
  float x0 = m4.x > 0 ? v.x : NEG;
  float x1 = m4.y > 0 ? v.y : NEG;
  float x2 = m4.z > 0 ? v.z : NEG;
  float x3 = m4.w > 0 ? v.w : NEG;
  float mx = fmaxf(fmaxf(x0, x1), fmaxf(x2, x3));
  #pragma unroll
  for (int off = 1; off < 64; off <<= 1) mx = fmaxf(mx, __shfl_xor(mx, off));
  float sum = expf(x0 - mx) + expf(x1 - mx) + expf(x2 - mx) + expf(x3 - mx);
  #pragma unroll
  for (int off = 1; off < 64; off <<= 1) sum += __shfl_xor(sum, off);
  if (lane == 0) { rmax[row] = mx; rinv[row] = 1.0f / sum; }
}

// ---------------- K4a: column softmax partial stats over c (axis 1) ----------------
// grid (16 chunks, B), block 256 (thread = q). each scans 128 c's, online max/sum.
__global__ __launch_bounds__(256) void k4a_colpart(
    const float* __restrict__ s, const int* __restrict__ cmask,
    float* __restrict__ pmax, float* __restrict__ psum) {
  int chunk = blockIdx.x, b = blockIdx.y, q = threadIdx.x;
  const float* sp = s + ((size_t)b * CL + chunk * 128) * QL + q;
  const int* cm = cmask + b * CL + chunk * 128;
  float m = neginf(), l = 0.f;
  for (int c = 0; c < 128; ++c) {
    float x = cm[c] > 0 ? sp[(size_t)c * QL] : NEG;
    float nm = fmaxf(m, x);
    l = l * expf(m - nm) + expf(x - nm);
    m = nm;
  }
  int o = (b * 16 + chunk) * QL + q;
  pmax[o] = m;
  psum[o] = l;
}

// ---------------- K4b: combine column partials ----------------
__global__ __launch_bounds__(256) void k4b_colreduce(
    const float* __restrict__ pmax, const float* __restrict__ psum,
    float* __restrict__ cmax, float* __restrict__ cinv) {
  int idx = blockIdx.x * 256 + threadIdx.x;  // b*QL + q
  if (idx >= B * QL) return;
  int b = idx / QL, q = idx % QL;
  float M = neginf();
  #pragma unroll
  for (int k = 0; k < 16; ++k) M = fmaxf(M, pmax[(b * 16 + k) * QL + q]);
  float L = 0.f;
  #pragma unroll
  for (int k = 0; k < 16; ++k)
    L += psum[(b * 16 + k) * QL + q] * expf(pmax[(b * 16 + k) * QL + q] - M);
  cmax[idx] = M;
  cinv[idx] = 1.0f / L;
}

// ---------------- K5a: t partials. t[b,q,h] = sum_c s2[b,c,q]*ctx[b,h,c] ----------------
// grid (H/64, QL/64, SPLITC*B), block 256, 4x4 per thread, c chunked by 32.
__global__ __launch_bounds__(256) void k5a_tpart(
    const float* __restrict__ s, const float* __restrict__ ctx,
    const int* __restrict__ cmask, const float* __restrict__ cmax,
    const float* __restrict__ cinv, float* __restrict__ tpart) {
  __shared__ float Ss[32][64];   // Ss[kk][qq] = exp(s[c0+kk, q0+qq]-cmax[q])
  __shared__ float Cs[64][33];   // Cs[hh][kk] = ctx[b, h0+hh, cbase+kk]
  const int bz = blockIdx.z;          // split*B + b
  const int b = bz & (B - 1);
  const int q0 = blockIdx.y * 64;
  const int h0 = blockIdx.x * 64;
  const int tid = threadIdx.x;
  const int tx = tid & 15, ty = tid >> 4;
  const int cbase = (bz >> 4) * (CL / SPLITC);
  const float* sb = s + (size_t)b * CL * QL;
  const float* ctxb = ctx + (size_t)b * H * CL;
  float acc[4][4] = {};
  for (int cc0 = cbase; cc0 < cbase + CL / SPLITC; cc0 += 32) {
    #pragma unroll
    for (int i = 0; i < 8; ++i) {
      int lin = i * 256 + tid;
      int kk = lin >> 6, qq = lin & 63;
      int c = cc0 + kk, q = q0 + qq;
      float x = cmask[b * CL + c] > 0 ? sb[(size_t)c * QL + q] : NEG;
      Ss[kk][qq] = expf(x - cmax[b * QL + q]);
      int hh = lin >> 5, k2 = lin & 31;
      Cs[hh][k2] = ctxb[(size_t)(h0 + hh) * CL + cc0 + k2];
    }
    __syncthreads();
    #pragma unroll
    for (int kk = 0; kk < 32; ++kk) {
      float sv[4], cv[4];
      #pragma unroll
      for (int i = 0; i < 4; ++i) sv[i] = Ss[kk][ty * 4 + i];
      #pragma unroll
      for (int j = 0; j < 4; ++j) cv[j] = Cs[tx * 4 + j][kk];
      #pragma unroll
      for (int i = 0; i < 4; ++i)
        #pragma unroll
        for (int j = 0; j < 4; ++j) acc[i][j] = fmaf(sv[i], cv[j], acc[i][j]);
    }
    __syncthreads();
  }
  float* tp = tpart + (size_t)bz * QL * H;
  #pragma unroll
  for (int i = 0; i < 4; ++i) {
    int q = q0 + ty * 4 + i;
    float ci = cinv[b * QL + q];
    float4 v;
    v.x = acc[i][0] * ci;
    v.y = acc[i][1] * ci;
    v.z = acc[i][2] * ci;
    v.w = acc[i][3] * ci;
    *(float4*)&tp[(size_t)q * H + h0 + tx * 4] = v;
  }
}

// ---------------- K5b: reduce t partials ----------------
__global__ __launch_bounds__(256) void k5b_treduce(
    const float* __restrict__ tpart, float* __restrict__ t) {
  int idx = blockIdx.x * 256 + threadIdx.x;
  if (idx >= B * QL * H) return;
  float v = 0.f;
  #pragma unroll
  for (int k = 0; k < SPLITC; ++k) v += tpart[(size_t)k * B * QL * H + idx];
  t[idx] = v;
}

// ---------------- K6: a = s1@qry^T, bb = s1@t; fused transpose epilogue ----------------
// grid (H/64, CL/64, B), block 256. writes all 4 output groups.
union K6SM {
  struct { float S1s[64][33]; float Qs[64][33]; float Ts[32][64]; } st;
  struct { float At[64][65]; float Bt[64][65]; } tr;
};
__global__ __launch_bounds__(256) void k6_out(
    const float* __restrict__ s, const float* __restrict__ qry,
    const float* __restrict__ t, const float* __restrict__ ctx,
    const int* __restrict__ qmask, const float* __restrict__ rmax,
    const float* __restrict__ rinv, float* __restrict__ out) {
  __shared__ K6SM sm;
  const int b = blockIdx.z;
  const int c0 = blockIdx.y * 64;
  const int h0 = blockIdx.x * 64;
  const int tid = threadIdx.x;
  const int tx = tid & 15, ty = tid >> 4;
  const float* sb = s + (size_t)b * CL * QL;
  const float* qb = qry + (size_t)b * H * QL;
  const float* tb = t + (size_t)b * QL * H;
  float accA[4][4] = {}, accB[4][4] = {};
  for (int q0 = 0; q0 < QL; q0 += 32) {
    #pragma unroll
    for (int i = 0; i < 8; ++i) {
      int lin = i * 256 + tid;
      int cc = lin >> 5, kk = lin & 31;
      int c = c0 + cc, q = q0 + kk;
      float x = qmask[b * QL + q] > 0 ? sb[(size_t)c * QL + q] : NEG;
      sm.st.S1s[cc][kk] = expf(x - rmax[b * CL + c]);
      sm.st.Qs[cc][kk] = qb[(h0 + cc) * QL + q];  // cc plays hh here
      int kk2 = lin >> 6, hh2 = lin & 63;
      sm.st.Ts[kk2][hh2] = tb[(q0 + kk2) * H + h0 + hh2];
    }
    __syncthreads();
    #pragma unroll
    for (int kk = 0; kk < 32; ++kk) {
      float sv[4], qv[4], tv[4];
      #pragma unroll
      for (int i = 0; i < 4; ++i) sv[i] = sm.st.S1s[ty * 4 + i][kk];
      #pragma unroll
      for (int j = 0; j < 4; ++j) qv[j] = sm.st.Qs[tx * 4 + j][kk];
      #pragma unroll
      for (int j = 0; j < 4; ++j) tv[j] = sm.st.Ts[kk][tx * 4 + j];
      #pragma unroll
      for (int i = 0; i < 4; ++i)
        #pragma unroll
        for (int j = 0; j < 4; ++j) {
          accA[i][j] = fmaf(sv[i], qv[j], accA[i][j]);
          accB[i][j] = fmaf(sv[i], tv[j], accB[i][j]);
        }
    }
    __syncthreads();
  }
  float rv[4];
  #pragma unroll
  for (int i = 0; i < 4; ++i) rv[i] = rinv[b * CL + c0 + ty * 4 + i];
  // transpose through LDS (union reuse is safe: synced after last staging read)
  #pragma unroll
  for (int i = 0; i < 4; ++i)
    #pragma unroll
    for (int j = 0; j < 4; ++j) {
      sm.tr.At[tx * 4 + j][ty * 4 + i] = accA[i][j] * rv[i];
      sm.tr.Bt[tx * 4 + j][ty * 4 + i] = accB[i][j] * rv[i];
    }
  __syncthreads();
  const float* ctxb = ctx + (size_t)b * H * CL;
  float* ob = out + (size_t)b * 4 * H * CL;
  int cc = tid & 63;
  int hbase = tid >> 6;
  #pragma unroll
  for (int r = 0; r < 16; ++r) {
    int hh = r * 4 + hbase;
    int h = h0 + hh, c = c0 + cc;
    float cv = ctxb[(size_t)h * CL + c];
    float av = sm.tr.At[hh][cc];
    float bv = sm.tr.Bt[hh][cc];
    ob[(size_t)h * CL + c] = cv;
    ob[(size_t)(H + h) * CL + c] = av;
    ob[(size_t)(2 * H + h) * CL + c] = cv * av;
    ob[(size_t)(3 * H + h) * CL + c] = cv * bv;
  }
}

extern "C" void kernel_launch(void* const* d_in, const int* in_sizes, int n_in,
                              void* d_out, int out_size, void* d_ws, size_t ws_size,
                              hipStream_t stream) {
  const float* context  = (const float*)d_in[0];
  const float* question = (const float*)d_in[1];
  const int*   c_mask   = (const int*)d_in[2];
  const int*   q_mask   = (const int*)d_in[3];
  const float* w        = (const float*)d_in[4];
  float* out = (float*)d_out;

  char* ws = (char*)d_ws;
  size_t off = 0;
  auto alloc = [&](size_t bytes) -> void* {
    void* p = ws + off;
    off += (bytes + 255) & ~(size_t)255;
    return p;
  };
  float* s_buf = (float*)alloc((size_t)B * CL * QL * sizeof(float));   // 33.5 MB
  float* cterm = (float*)alloc((size_t)B * CL * sizeof(float));
  float* qterm = (float*)alloc((size_t)B * QL * sizeof(float));
  float* rmax_ = (float*)alloc((size_t)B * CL * sizeof(float));
  float* rinv_ = (float*)alloc((size_t)B * CL * sizeof(float));
  float* cmax_ = (float*)alloc((size_t)B * QL * sizeof(float));
  float* cinv_ = (float*)alloc((size_t)B * QL * sizeof(float));
  float* pmax_ = (float*)alloc((size_t)B * 16 * QL * sizeof(float));
  float* psum_ = (float*)alloc((size_t)B * 16 * QL * sizeof(float));
  float* tpart = (float*)alloc((size_t)SPLITC * B * QL * H * sizeof(float)); // 8 MB
  float* t_buf = (float*)alloc((size_t)B * QL * H * sizeof(float));          // 2 MB

  k1_bias<<<dim3((B * CL + B * QL + 255) / 256), dim3(256), 0, stream>>>(
      context, question, w, cterm, qterm);

  k2_score<<<dim3(QL / 64, CL / 64, B), dim3(256), 0, stream>>>(
      context, question, w, cterm, qterm, s_buf);

  k3_rowstats<<<dim3(B * CL / 4), dim3(256), 0, stream>>>(
      s_buf, q_mask, rmax_, rinv_);

  k4a_colpart<<<dim3(16, B), dim3(256), 0, stream>>>(
      s_buf, c_mask, pmax_, psum_);

  k4b_colreduce<<<dim3((B * QL + 255) / 256), dim3(256), 0, stream>>>(
      pmax_, psum_, cmax_, cinv_);

  k5a_tpart<<<dim3(H / 64, QL / 64, SPLITC * B), dim3(256), 0, stream>>>(
      s_buf, context, c_mask, cmax_, cinv_, tpart);

  k5b_treduce<<<dim3((B * QL * H + 255) / 256), dim3(256), 0, stream>>>(
      tpart, t_buf);

  k6_out<<<dim3(H / 64, CL / 64, B), dim3(256), 0, stream>>>(
      s_buf, question, t_buf, context, q_mask, rmax_, rinv_, out);
}

// Round 2
// 381.798 us; speedup vs baseline: 1.0820x; 1.0820x over previous
//
#include <hip/hip_runtime.h>

constexpr int B  = 16;
constexpr int H  = 128;
constexpr int CL = 2048;
constexpr int QL = 256;
constexpr int SPLITC = 4;
constexpr int K4CHUNK = 32;            // c's per k4a block
constexpr int K4N = CL / K4CHUNK;      // 64 partials
constexpr float NEG = -1e30f;

__device__ __forceinline__ float neginf() { return -__builtin_inff(); }

// ---------------- K1: bias terms cterm[b,c], qterm[b,q] ----------------
__global__ __launch_bounds__(256) void k1_bias(
    const float* __restrict__ ctx, const float* __restrict__ qry,
    const float* __restrict__ w,
    float* __restrict__ cterm, float* __restrict__ qterm) {
  int idx = blockIdx.x * 256 + threadIdx.x;
  if (idx < B * CL) {
    int b = idx / CL, c = idx % CL;
    const float* p = ctx + (size_t)b * H * CL + c;
    float acc = 0.f;
    #pragma unroll 8
    for (int h = 0; h < H; ++h) acc = fmaf(p[(size_t)h * CL], w[H + h], acc);
    cterm[idx] = acc;
  } else if (idx < B * CL + B * QL) {
    int i2 = idx - B * CL;
    int b = i2 / QL, q = i2 % QL;
    const float* p = qry + (size_t)b * H * QL + q;
    float acc = 0.f;
    #pragma unroll 8
    for (int h = 0; h < H; ++h) acc = fmaf(p[h * QL], w[h], acc);
    qterm[i2] = acc;
  }
}

// ---------------- K2: s[b,c,q] = cterm + qterm + (ctx*wcq)^T @ qry ----------------
__global__ __launch_bounds__(256) void k2_score(
    const float* __restrict__ ctx, const float* __restrict__ qry,
    const float* __restrict__ w, const float* __restrict__ cterm,
    const float* __restrict__ qterm, float* __restrict__ s_out) {
  __shared__ float As[32][64];
  __shared__ float Bs[32][64];
  const int b  = blockIdx.z;
  const int c0 = blockIdx.y * 64;
  const int q0 = blockIdx.x * 64;
  const int tid = threadIdx.x;
  const int tx = tid & 15, ty = tid >> 4;
  const float* ctxb = ctx + (size_t)b * H * CL;
  const float* qryb = qry + (size_t)b * H * QL;
  float acc[4][4] = {};
  for (int h0 = 0; h0 < H; h0 += 32) {
    #pragma unroll
    for (int i = 0; i < 8; ++i) {
      int lin = i * 256 + tid;
      int kk = lin >> 6, cc = lin & 63;
      As[kk][cc] = ctxb[(size_t)(h0 + kk) * CL + c0 + cc] * w[2 * H + h0 + kk];
      Bs[kk][cc] = qryb[(h0 + kk) * QL + q0 + cc];
    }
    __syncthreads();
    #pragma unroll
    for (int kk = 0; kk < 32; ++kk) {
      float a[4], bq[4];
      #pragma unroll
      for (int i = 0; i < 4; ++i) a[i] = As[kk][ty * 4 + i];
      #pragma unroll
      for (int j = 0; j < 4; ++j) bq[j] = Bs[kk][tx * 4 + j];
      #pragma unroll
      for (int i = 0; i < 4; ++i)
        #pragma unroll
        for (int j = 0; j < 4; ++j) acc[i][j] = fmaf(a[i], bq[j], acc[i][j]);
    }
    __syncthreads();
  }
  float qt[4];
  #pragma unroll
  for (int j = 0; j < 4; ++j) qt[j] = qterm[b * QL + q0 + tx * 4 + j];
  #pragma unroll
  for (int i = 0; i < 4; ++i) {
    int c = c0 + ty * 4 + i;
    float ct = cterm[b * CL + c];
    float4 v;
    v.x = acc[i][0] + ct + qt[0];
    v.y = acc[i][1] + ct + qt[1];
    v.z = acc[i][2] + ct + qt[2];
    v.w = acc[i][3] + ct + qt[3];
    *(float4*)&s_out[((size_t)b * CL + c) * QL + q0 + tx * 4] = v;
  }
}

// ---------------- K3: row softmax stats over q (axis 2) ----------------
__global__ __launch_bounds__(256) void k3_rowstats(
    const float* __restrict__ s, const int* __restrict__ qmask,
    float* __restrict__ rmax, float* __restrict__ rinv) {
  int row = blockIdx.x * 4 + (threadIdx.x >> 6);  // b*CL + c
  int lane = threadIdx.x & 63;
  int b = row / CL;
  const float* sp = s + (size_t)row * QL;
  float4 v = *(const float4*)&sp[lane * 4];
  int4 m4 = *(const int4*)&qmask[b * QL + lane * 4];
  float x0 = m4.x > 0 ? v.x : NEG;
  float x1 = m4.y > 0 ? v.y : NEG;
  float x2 = m4.z > 0 ? v.z : NEG;
  float x3 = m4.w > 0 ? v.w : NEG;
  float mx = fmaxf(fmaxf(x0, x1), fmaxf(x2, x3));
  #pragma unroll
  for (int off = 1; off < 64; off <<= 1) mx = fmaxf(mx, __shfl_xor(mx, off));
  float sum = expf(x0 - mx) + expf(x1 - mx) + expf(x2 - mx) + expf(x3 - mx);
  #pragma unroll
  for (int off = 1; off < 64; off <<= 1) sum += __shfl_xor(sum, off);
  if (lane == 0) { rmax[row] = mx; rinv[row] = 1.0f / sum; }
}

// ---------------- K4a: column softmax partial stats (two-pass, regs) ----------------
// grid (K4N, B), block 256 (thread = q). each handles K4CHUNK c's held in registers.
__global__ __launch_bounds__(256) void k4a_colpart(
    const float* __restrict__ s, const int* __restrict__ cmask,
    float* __restrict__ pmax, float* __restrict__ psum) {
  int chunk = blockIdx.x, b = blockIdx.y, q = threadIdx.x;
  const float* sp = s + ((size_t)b * CL + chunk * K4CHUNK) * QL + q;
  const int* cm = cmask + b * CL + chunk * K4CHUNK;
  float x[K4CHUNK];
  #pragma unroll
  for (int c = 0; c < K4CHUNK; ++c)
    x[c] = cm[c] > 0 ? sp[(size_t)c * QL] : NEG;
  float m0 = NEG, m1 = NEG, m2 = NEG, m3 = NEG;
  #pragma unroll
  for (int c = 0; c < K4CHUNK; c += 4) {
    m0 = fmaxf(m0, x[c]);     m1 = fmaxf(m1, x[c + 1]);
    m2 = fmaxf(m2, x[c + 2]); m3 = fmaxf(m3, x[c + 3]);
  }
  float M = fmaxf(fmaxf(m0, m1), fmaxf(m2, m3));
  float l0 = 0, l1 = 0, l2 = 0, l3 = 0;
  #pragma unroll
  for (int c = 0; c < K4CHUNK; c += 4) {
    l0 += expf(x[c] - M);     l1 += expf(x[c + 1] - M);
    l2 += expf(x[c + 2] - M); l3 += expf(x[c + 3] - M);
  }
  int o = (b * K4N + chunk) * QL + q;
  pmax[o] = M;
  psum[o] = l0 + l1 + l2 + l3;
}

// ---------------- K4b: combine column partials ----------------
__global__ __launch_bounds__(256) void k4b_colreduce(
    const float* __restrict__ pmax, const float* __restrict__ psum,
    float* __restrict__ cmax, float* __restrict__ cinv) {
  int idx = blockIdx.x * 256 + threadIdx.x;  // b*QL + q
  if (idx >= B * QL) return;
  int b = idx / QL, q = idx % QL;
  float M = neginf();
  #pragma unroll 8
  for (int k = 0; k < K4N; ++k) M = fmaxf(M, pmax[(b * K4N + k) * QL + q]);
  float L = 0.f;
  #pragma unroll 8
  for (int k = 0; k < K4N; ++k)
    L += psum[(b * K4N + k) * QL + q] * expf(pmax[(b * K4N + k) * QL + q] - M);
  cmax[idx] = M;
  cinv[idx] = 1.0f / L;
}

// ---------------- K5a: t partials. t[b,q,h] = sum_c s2[b,c,q]*ctx[b,h,c] ----------------
__global__ __launch_bounds__(256) void k5a_tpart(
    const float* __restrict__ s, const float* __restrict__ ctx,
    const int* __restrict__ cmask, const float* __restrict__ cmax,
    const float* __restrict__ cinv, float* __restrict__ tpart) {
  __shared__ float Ss[32][64];   // Ss[kk][qq] = exp(s[c0+kk, q0+qq]-cmax[q])
  __shared__ float Cs[64][33];   // Cs[hh][kk] = ctx[b, h0+hh, cbase+kk]
  const int bz = blockIdx.z;
  const int b = bz & (B - 1);
  const int q0 = blockIdx.y * 64;
  const int h0 = blockIdx.x * 64;
  const int tid = threadIdx.x;
  const int tx = tid & 15, ty = tid >> 4;
  const int cbase = (bz >> 4) * (CL / SPLITC);
  const float* sb = s + (size_t)b * CL * QL;
  const float* ctxb = ctx + (size_t)b * H * CL;
  float acc[4][4] = {};
  for (int cc0 = cbase; cc0 < cbase + CL / SPLITC; cc0 += 32) {
    #pragma unroll
    for (int i = 0; i < 8; ++i) {
      int lin = i * 256 + tid;
      int kk = lin >> 6, qq = lin & 63;
      int c = cc0 + kk, q = q0 + qq;
      float x = cmask[b * CL + c] > 0 ? sb[(size_t)c * QL + q] : NEG;
      Ss[kk][qq] = expf(x - cmax[b * QL + q]);
      int hh = lin >> 5, k2 = lin & 31;
      Cs[hh][k2] = ctxb[(size_t)(h0 + hh) * CL + cc0 + k2];
    }
    __syncthreads();
    #pragma unroll
    for (int kk = 0; kk < 32; ++kk) {
      float sv[4], cv[4];
      #pragma unroll
      for (int i = 0; i < 4; ++i) sv[i] = Ss[kk][ty * 4 + i];
      #pragma unroll
      for (int j = 0; j < 4; ++j) cv[j] = Cs[tx * 4 + j][kk];
      #pragma unroll
      for (int i = 0; i < 4; ++i)
        #pragma unroll
        for (int j = 0; j < 4; ++j) acc[i][j] = fmaf(sv[i], cv[j], acc[i][j]);
    }
    __syncthreads();
  }
  float* tp = tpart + (size_t)bz * QL * H;
  #pragma unroll
  for (int i = 0; i < 4; ++i) {
    int q = q0 + ty * 4 + i;
    float ci = cinv[b * QL + q];
    float4 v;
    v.x = acc[i][0] * ci;
    v.y = acc[i][1] * ci;
    v.z = acc[i][2] * ci;
    v.w = acc[i][3] * ci;
    *(float4*)&tp[(size_t)q * H + h0 + tx * 4] = v;
  }
}

// ---------------- K5b: reduce t partials ----------------
__global__ __launch_bounds__(256) void k5b_treduce(
    const float* __restrict__ tpart, float* __restrict__ t) {
  int idx = blockIdx.x * 256 + threadIdx.x;
  if (idx >= B * QL * H) return;
  float v = 0.f;
  #pragma unroll
  for (int k = 0; k < SPLITC; ++k) v += tpart[(size_t)k * B * QL * H + idx];
  t[idx] = v;
}

// ---------------- K6: transposed dual-GEMM, direct coalesced epilogue ----------------
// aT[h,c] = sum_q qry[h,q]*s1[c,q];  bT[h,c] = sum_q t[q,h]*s1[c,q]
// grid (H/64, CL/64, B), block 256, 4h x 4c per thread. No LDS transpose.
__global__ __launch_bounds__(256) void k6_out(
    const float* __restrict__ s, const float* __restrict__ qry,
    const float* __restrict__ t, const float* __restrict__ ctx,
    const int* __restrict__ qmask, const float* __restrict__ rmax,
    const float* __restrict__ rinv, float* __restrict__ out) {
  __shared__ float Ss[32][65];  // [q][c]: s1 tile = exp(s-rmax)*rinv
  __shared__ float Qs[32][65];  // [q][h]: qry^T tile
  __shared__ float Ts[32][65];  // [q][h]: t tile (native layout)
  const int b = blockIdx.z;
  const int h0 = blockIdx.x * 64;
  const int c0 = blockIdx.y * 64;
  const int tid = threadIdx.x;
  const int tx = tid & 15, ty = tid >> 4;   // tx -> c, ty -> h
  const float* sb = s + (size_t)b * CL * QL;
  const float* qb = qry + (size_t)b * H * QL;
  const float* tb = t + (size_t)b * QL * H;
  const int* qm = qmask + b * QL;
  const float* rmx = rmax + b * CL;
  const float* riv = rinv + b * CL;
  float accA[4][4] = {}, accB[4][4] = {};
  for (int q0 = 0; q0 < QL; q0 += 32) {
    #pragma unroll
    for (int i = 0; i < 8; ++i) {
      int lin = i * 256 + tid;
      int row = lin >> 5, q = lin & 31;      // row: c-off or h-off
      float x = qm[q0 + q] > 0 ? sb[(size_t)(c0 + row) * QL + q0 + q] : NEG;
      Ss[q][row] = expf(x - rmx[c0 + row]) * riv[c0 + row];
      Qs[q][row] = qb[(h0 + row) * QL + q0 + q];
      int q2 = lin >> 6, h2 = lin & 63;
      Ts[q2][h2] = tb[(q0 + q2) * H + h0 + h2];
    }
    __syncthreads();
    #pragma unroll
    for (int kk = 0; kk < 32; ++kk) {
      float hq[4], ht[4], cs[4];
      #pragma unroll
      for (int i = 0; i < 4; ++i) { hq[i] = Qs[kk][ty * 4 + i]; ht[i] = Ts[kk][ty * 4 + i]; }
      #pragma unroll
      for (int j = 0; j < 4; ++j) cs[j] = Ss[kk][tx * 4 + j];
      #pragma unroll
      for (int i = 0; i < 4; ++i)
        #pragma unroll
        for (int j = 0; j < 4; ++j) {
          accA[i][j] = fmaf(hq[i], cs[j], accA[i][j]);
          accB[i][j] = fmaf(ht[i], cs[j], accB[i][j]);
        }
    }
    __syncthreads();
  }
  const float* ctxb = ctx + (size_t)b * H * CL;
  float* ob = out + (size_t)b * 4 * H * CL;
  #pragma unroll
  for (int i = 0; i < 4; ++i) {
    int h = h0 + ty * 4 + i;
    int c = c0 + tx * 4;
    float4 cv = *(const float4*)&ctxb[(size_t)h * CL + c];
    float4 av = make_float4(accA[i][0], accA[i][1], accA[i][2], accA[i][3]);
    float4 bv = make_float4(accB[i][0], accB[i][1], accB[i][2], accB[i][3]);
    float4 ca = make_float4(cv.x * av.x, cv.y * av.y, cv.z * av.z, cv.w * av.w);
    float4 cb = make_float4(cv.x * bv.x, cv.y * bv.y, cv.z * bv.z, cv.w * bv.w);
    *(float4*)&ob[(size_t)h * CL + c] = cv;
    *(float4*)&ob[(size_t)(H + h) * CL + c] = av;
    *(float4*)&ob[(size_t)(2 * H + h) * CL + c] = ca;
    *(float4*)&ob[(size_t)(3 * H + h) * CL + c] = cb;
  }
}

extern "C" void kernel_launch(void* const* d_in, const int* in_sizes, int n_in,
                              void* d_out, int out_size, void* d_ws, size_t ws_size,
                              hipStream_t stream) {
  const float* context  = (const float*)d_in[0];
  const float* question = (const float*)d_in[1];
  const int*   c_mask   = (const int*)d_in[2];
  const int*   q_mask   = (const int*)d_in[3];
  const float* w        = (const float*)d_in[4];
  float* out = (float*)d_out;

  char* ws = (char*)d_ws;
  size_t off = 0;
  auto alloc = [&](size_t bytes) -> void* {
    void* p = ws + off;
    off += (bytes + 255) & ~(size_t)255;
    return p;
  };
  float* s_buf = (float*)alloc((size_t)B * CL * QL * sizeof(float));
  float* cterm = (float*)alloc((size_t)B * CL * sizeof(float));
  float* qterm = (float*)alloc((size_t)B * QL * sizeof(float));
  float* rmax_ = (float*)alloc((size_t)B * CL * sizeof(float));
  float* rinv_ = (float*)alloc((size_t)B * CL * sizeof(float));
  float* cmax_ = (float*)alloc((size_t)B * QL * sizeof(float));
  float* cinv_ = (float*)alloc((size_t)B * QL * sizeof(float));
  float* pmax_ = (float*)alloc((size_t)B * K4N * QL * sizeof(float));
  float* psum_ = (float*)alloc((size_t)B * K4N * QL * sizeof(float));
  float* tpart = (float*)alloc((size_t)SPLITC * B * QL * H * sizeof(float));
  float* t_buf = (float*)alloc((size_t)B * QL * H * sizeof(float));

  k1_bias<<<dim3((B * CL + B * QL + 255) / 256), dim3(256), 0, stream>>>(
      context, question, w, cterm, qterm);

  k2_score<<<dim3(QL / 64, CL / 64, B), dim3(256), 0, stream>>>(
      context, question, w, cterm, qterm, s_buf);

  k3_rowstats<<<dim3(B * CL / 4), dim3(256), 0, stream>>>(
      s_buf, q_mask, rmax_, rinv_);

  k4a_colpart<<<dim3(K4N, B), dim3(256), 0, stream>>>(
      s_buf, c_mask, pmax_, psum_);

  k4b_colreduce<<<dim3((B * QL + 255) / 256), dim3(256), 0, stream>>>(
      pmax_, psum_, cmax_, cinv_);

  k5a_tpart<<<dim3(H / 64, QL / 64, SPLITC * B), dim3(256), 0, stream>>>(
      s_buf, context, c_mask, cmax_, cinv_, tpart);

  k5b_treduce<<<dim3((B * QL * H + 255) / 256), dim3(256), 0, stream>>>(
      tpart, t_buf);

  k6_out<<<dim3(H / 64, CL / 64, B), dim3(256), 0, stream>>>(
      s_buf, question, t_buf, context, q_mask, rmax_, rinv_, out);
}

// Round 3
// 158.510 us; speedup vs baseline: 2.6062x; 2.4087x over previous
//
#include <hip/hip_runtime.h>

typedef short bf16x8 __attribute__((ext_vector_type(8)));   // 8 bf16 = 4 VGPRs
typedef float f32x16 __attribute__((ext_vector_type(16)));  // MFMA 32x32 acc

constexpr int B  = 16;
constexpr int H  = 128;
constexpr int CL = 2048;
constexpr int QL = 256;
constexpr int K4CHUNK = 32;
constexpr int K4N = CL / K4CHUNK;
constexpr int SPLITK5 = 8;
constexpr int K5SEG = CL / SPLITK5;   // 256
constexpr float NEG = -1e30f;

__device__ __forceinline__ float neginf() { return -__builtin_inff(); }

__device__ __forceinline__ unsigned short f2bf(float x) {
  unsigned u = __float_as_uint(x);
  u += 0x7fffu + ((u >> 16) & 1u);   // round-to-nearest-even
  return (unsigned short)(u >> 16);
}

// ---------------- KP: fp32 -> bf16 copies of ctx and qry ----------------
__global__ __launch_bounds__(256) void kprep(
    const float* __restrict__ ctx, const float* __restrict__ qry,
    unsigned short* __restrict__ ctx_bf, unsigned short* __restrict__ qry_bf) {
  const int NC = B * H * CL / 4, NQ = B * H * QL / 4;
  for (int i = blockIdx.x * 256 + threadIdx.x; i < NC + NQ; i += gridDim.x * 256) {
    if (i < NC) {
      float4 v = ((const float4*)ctx)[i];
      ushort4 o;
      o.x = f2bf(v.x); o.y = f2bf(v.y); o.z = f2bf(v.z); o.w = f2bf(v.w);
      ((ushort4*)ctx_bf)[i] = o;
    } else {
      float4 v = ((const float4*)qry)[i - NC];
      ushort4 o;
      o.x = f2bf(v.x); o.y = f2bf(v.y); o.z = f2bf(v.z); o.w = f2bf(v.w);
      ((ushort4*)qry_bf)[i - NC] = o;
    }
  }
}

// ---------------- K1: bias terms cterm[b,c], qterm[b,q] ----------------
__global__ __launch_bounds__(256) void k1_bias(
    const float* __restrict__ ctx, const float* __restrict__ qry,
    const float* __restrict__ w,
    float* __restrict__ cterm, float* __restrict__ qterm) {
  int idx = blockIdx.x * 256 + threadIdx.x;
  if (idx < B * CL) {
    int b = idx / CL, c = idx % CL;
    const float* p = ctx + (size_t)b * H * CL + c;
    float acc = 0.f;
    #pragma unroll 8
    for (int h = 0; h < H; ++h) acc = fmaf(p[(size_t)h * CL], w[H + h], acc);
    cterm[idx] = acc;
  } else if (idx < B * CL + B * QL) {
    int i2 = idx - B * CL;
    int b = i2 / QL, q = i2 % QL;
    const float* p = qry + (size_t)b * H * QL + q;
    float acc = 0.f;
    #pragma unroll 8
    for (int h = 0; h < H; ++h) acc = fmaf(p[h * QL], w[h], acc);
    qterm[i2] = acc;
  }
}

// ---------------- K2: s[b,c,q] = cterm + qterm + (ctx*wcq)^T @ qry (fp32) ----------------
__global__ __launch_bounds__(256) void k2_score(
    const float* __restrict__ ctx, const float* __restrict__ qry,
    const float* __restrict__ w, const float* __restrict__ cterm,
    const float* __restrict__ qterm, float* __restrict__ s_out) {
  __shared__ float As[32][64];
  __shared__ float Bs[32][64];
  const int b  = blockIdx.z;
  const int c0 = blockIdx.y * 64;
  const int q0 = blockIdx.x * 64;
  const int tid = threadIdx.x;
  const int tx = tid & 15, ty = tid >> 4;
  const float* ctxb = ctx + (size_t)b * H * CL;
  const float* qryb = qry + (size_t)b * H * QL;
  float acc[4][4] = {};
  for (int h0 = 0; h0 < H; h0 += 32) {
    #pragma unroll
    for (int i = 0; i < 8; ++i) {
      int lin = i * 256 + tid;
      int kk = lin >> 6, cc = lin & 63;
      As[kk][cc] = ctxb[(size_t)(h0 + kk) * CL + c0 + cc] * w[2 * H + h0 + kk];
      Bs[kk][cc] = qryb[(h0 + kk) * QL + q0 + cc];
    }
    __syncthreads();
    #pragma unroll
    for (int kk = 0; kk < 32; ++kk) {
      float a[4], bq[4];
      #pragma unroll
      for (int i = 0; i < 4; ++i) a[i] = As[kk][ty * 4 + i];
      #pragma unroll
      for (int j = 0; j < 4; ++j) bq[j] = Bs[kk][tx * 4 + j];
      #pragma unroll
      for (int i = 0; i < 4; ++i)
        #pragma unroll
        for (int j = 0; j < 4; ++j) acc[i][j] = fmaf(a[i], bq[j], acc[i][j]);
    }
    __syncthreads();
  }
  float qt[4];
  #pragma unroll
  for (int j = 0; j < 4; ++j) qt[j] = qterm[b * QL + q0 + tx * 4 + j];
  #pragma unroll
  for (int i = 0; i < 4; ++i) {
    int c = c0 + ty * 4 + i;
    float ct = cterm[b * CL + c];
    float4 v;
    v.x = acc[i][0] + ct + qt[0];
    v.y = acc[i][1] + ct + qt[1];
    v.z = acc[i][2] + ct + qt[2];
    v.w = acc[i][3] + ct + qt[3];
    *(float4*)&s_out[((size_t)b * CL + c) * QL + q0 + tx * 4] = v;
  }
}

// ---------------- K3: row softmax stats + write s1_bf[c][q] ----------------
__global__ __launch_bounds__(256) void k3_rowstats(
    const float* __restrict__ s, const int* __restrict__ qmask,
    unsigned short* __restrict__ s1bf) {
  int row = blockIdx.x * 4 + (threadIdx.x >> 6);  // b*CL + c
  int lane = threadIdx.x & 63;
  int b = row / CL;
  const float* sp = s + (size_t)row * QL;
  float4 v = *(const float4*)&sp[lane * 4];
  int4 m4 = *(const int4*)&qmask[b * QL + lane * 4];
  float x0 = m4.x > 0 ? v.x : NEG;
  float x1 = m4.y > 0 ? v.y : NEG;
  float x2 = m4.z > 0 ? v.z : NEG;
  float x3 = m4.w > 0 ? v.w : NEG;
  float mx = fmaxf(fmaxf(x0, x1), fmaxf(x2, x3));
  #pragma unroll
  for (int off = 1; off < 64; off <<= 1) mx = fmaxf(mx, __shfl_xor(mx, off));
  float e0 = expf(x0 - mx), e1 = expf(x1 - mx);
  float e2 = expf(x2 - mx), e3 = expf(x3 - mx);
  float sum = e0 + e1 + e2 + e3;
  #pragma unroll
  for (int off = 1; off < 64; off <<= 1) sum += __shfl_xor(sum, off);
  float rinv = 1.0f / sum;
  ushort4 o;
  o.x = f2bf(e0 * rinv); o.y = f2bf(e1 * rinv);
  o.z = f2bf(e2 * rinv); o.w = f2bf(e3 * rinv);
  *(ushort4*)&s1bf[(size_t)row * QL + lane * 4] = o;
}

// ---------------- K4a: column softmax partial stats ----------------
__global__ __launch_bounds__(256) void k4a_colpart(
    const float* __restrict__ s, const int* __restrict__ cmask,
    float* __restrict__ pmax, float* __restrict__ psum) {
  int chunk = blockIdx.x, b = blockIdx.y, q = threadIdx.x;
  const float* sp = s + ((size_t)b * CL + chunk * K4CHUNK) * QL + q;
  const int* cm = cmask + b * CL + chunk * K4CHUNK;
  float x[K4CHUNK];
  #pragma unroll
  for (int c = 0; c < K4CHUNK; ++c)
    x[c] = cm[c] > 0 ? sp[(size_t)c * QL] : NEG;
  float m0 = NEG, m1 = NEG, m2 = NEG, m3 = NEG;
  #pragma unroll
  for (int c = 0; c < K4CHUNK; c += 4) {
    m0 = fmaxf(m0, x[c]);     m1 = fmaxf(m1, x[c + 1]);
    m2 = fmaxf(m2, x[c + 2]); m3 = fmaxf(m3, x[c + 3]);
  }
  float M = fmaxf(fmaxf(m0, m1), fmaxf(m2, m3));
  float l0 = 0, l1 = 0, l2 = 0, l3 = 0;
  #pragma unroll
  for (int c = 0; c < K4CHUNK; c += 4) {
    l0 += expf(x[c] - M);     l1 += expf(x[c + 1] - M);
    l2 += expf(x[c + 2] - M); l3 += expf(x[c + 3] - M);
  }
  int o = (b * K4N + chunk) * QL + q;
  pmax[o] = M;
  psum[o] = l0 + l1 + l2 + l3;
}

// ---------------- K4b: combine column partials ----------------
__global__ __launch_bounds__(256) void k4b_colreduce(
    const float* __restrict__ pmax, const float* __restrict__ psum,
    float* __restrict__ cmax, float* __restrict__ cinv) {
  int idx = blockIdx.x * 256 + threadIdx.x;  // b*QL + q
  if (idx >= B * QL) return;
  int b = idx / QL, q = idx % QL;
  float M = neginf();
  #pragma unroll 8
  for (int k = 0; k < K4N; ++k) M = fmaxf(M, pmax[(b * K4N + k) * QL + q]);
  float L = 0.f;
  #pragma unroll 8
  for (int k = 0; k < K4N; ++k)
    L += psum[(b * K4N + k) * QL + q] * expf(pmax[(b * K4N + k) * QL + q] - M);
  cmax[idx] = M;
  cinv[idx] = 1.0f / L;
}

// ---------------- KE2: s2_bf[b][q][c] = bf16(exp(s-cmax)*cinv) (transpose) ----------------
__global__ __launch_bounds__(256) void kexp2(
    const float* __restrict__ s, const int* __restrict__ cmask,
    const float* __restrict__ cmax, const float* __restrict__ cinv,
    unsigned short* __restrict__ s2bf) {
  const int c0 = blockIdx.x * 32, b = blockIdx.y, q = threadIdx.x;
  const float cm = cmax[b * QL + q], ci = cinv[b * QL + q];
  const float* sp = s + ((size_t)b * CL + c0) * QL + q;
  const int* msk = cmask + b * CL + c0;
  ushort4 buf[8];
  #pragma unroll
  for (int cc = 0; cc < 32; cc += 4) {
    float x0 = msk[cc + 0] > 0 ? sp[(size_t)(cc + 0) * QL] : NEG;
    float x1 = msk[cc + 1] > 0 ? sp[(size_t)(cc + 1) * QL] : NEG;
    float x2 = msk[cc + 2] > 0 ? sp[(size_t)(cc + 2) * QL] : NEG;
    float x3 = msk[cc + 3] > 0 ? sp[(size_t)(cc + 3) * QL] : NEG;
    ushort4 o;
    o.x = f2bf(expf(x0 - cm) * ci); o.y = f2bf(expf(x1 - cm) * ci);
    o.z = f2bf(expf(x2 - cm) * ci); o.w = f2bf(expf(x3 - cm) * ci);
    buf[cc >> 2] = o;
  }
  unsigned short* op = s2bf + ((size_t)b * QL + q) * CL + c0;
  #pragma unroll
  for (int k = 0; k < 8; ++k) ((ushort4*)op)[k] = buf[k];
}

// ---------------- K5: MFMA tpart[seg][b][q][h] = sum_{c in seg} s2[q,c]*ctx[h,c] ----------------
// M=q(32), N=h(32), K=c. A frag = s2_bf[q][c..c+8], B frag = ctx_bf[h][c..c+8].
__global__ __launch_bounds__(256) void k5_tpart(
    const unsigned short* __restrict__ s2bf,
    const unsigned short* __restrict__ ctxbf,
    float* __restrict__ tpart) {
  const int q0 = blockIdx.x * 32;
  const int seg = blockIdx.y;
  const int b = blockIdx.z;
  const int w = threadIdx.x >> 6, l = threadIdx.x & 63;
  const int h0 = w * 32;
  const int lr = l & 31, lg = l >> 5;
  const unsigned short* ap = s2bf + ((size_t)b * QL + q0 + lr) * CL + seg * K5SEG + lg * 8;
  const unsigned short* bp = ctxbf + ((size_t)b * H + h0 + lr) * CL + seg * K5SEG + lg * 8;
  f32x16 acc = {};
  #pragma unroll
  for (int k = 0; k < K5SEG; k += 16) {
    bf16x8 af = *(const bf16x8*)(ap + k);
    bf16x8 bfr = *(const bf16x8*)(bp + k);
    acc = __builtin_amdgcn_mfma_f32_32x32x16_bf16(af, bfr, acc, 0, 0, 0);
  }
  float* tp = tpart + (size_t)(seg * B + b) * QL * H;
  #pragma unroll
  for (int r = 0; r < 16; ++r) {
    int qrow = (r & 3) + 8 * (r >> 2) + 4 * lg;
    tp[(size_t)(q0 + qrow) * H + h0 + lr] = acc[r];
  }
}

// ---------------- K5b: reduce tpart over segs, write tT_bf[b][h][q] ----------------
__global__ __launch_bounds__(256) void k5b_treduce(
    const float* __restrict__ tpart, unsigned short* __restrict__ tTbf) {
  __shared__ unsigned short lds[128 * 66];
  const int q0 = blockIdx.x * 64, b = blockIdx.y;
  const int tid = threadIdx.x;
  for (int lin = tid; lin < 64 * 128; lin += 256) {
    int q = lin >> 7, h = lin & 127;
    float v = 0.f;
    #pragma unroll
    for (int sgt = 0; sgt < SPLITK5; ++sgt)
      v += tpart[((size_t)(sgt * B + b) * QL + q0 + q) * H + h];
    lds[h * 66 + q] = f2bf(v);
  }
  __syncthreads();
  for (int lin = tid; lin < 64 * 128; lin += 256) {
    int h = lin >> 6, q = lin & 63;
    tTbf[((size_t)b * H + h) * QL + q0 + q] = lds[h * 66 + q];
  }
}

// ---------------- K6: MFMA dual-GEMM + fused output ----------------
// aT[h,c] = sum_q qry[h,q]*s1[c,q]; bT[h,c] = sum_q tT[h,q]*s1[c,q]
// M=h(32), N=c(32), K=q. Shared B frag = s1_bf[c][q..q+8]. No LDS.
__global__ __launch_bounds__(256) void k6_out(
    const unsigned short* __restrict__ s1bf,
    const unsigned short* __restrict__ qrybf,
    const unsigned short* __restrict__ tTbf,
    const float* __restrict__ ctx, float* __restrict__ out) {
  const int c0 = blockIdx.x * 32;
  const int b = blockIdx.y;
  const int w = threadIdx.x >> 6, l = threadIdx.x & 63;
  const int h0 = w * 32;
  const int lr = l & 31, lg = l >> 5;
  const unsigned short* bp  = s1bf  + ((size_t)b * CL + c0 + lr) * QL + lg * 8;
  const unsigned short* a1p = qrybf + ((size_t)b * H  + h0 + lr) * QL + lg * 8;
  const unsigned short* a2p = tTbf  + ((size_t)b * H  + h0 + lr) * QL + lg * 8;
  f32x16 accA = {}, accB = {};
  #pragma unroll
  for (int k = 0; k < QL; k += 16) {
    bf16x8 bfr = *(const bf16x8*)(bp + k);
    bf16x8 a1 = *(const bf16x8*)(a1p + k);
    bf16x8 a2 = *(const bf16x8*)(a2p + k);
    accA = __builtin_amdgcn_mfma_f32_32x32x16_bf16(a1, bfr, accA, 0, 0, 0);
    accB = __builtin_amdgcn_mfma_f32_32x32x16_bf16(a2, bfr, accB, 0, 0, 0);
  }
  const float* cb = ctx + (size_t)b * H * CL;
  float* ob = out + (size_t)b * 4 * H * CL;
  #pragma unroll
  for (int r = 0; r < 16; ++r) {
    int h = h0 + (r & 3) + 8 * (r >> 2) + 4 * lg;
    int c = c0 + lr;
    float cv = cb[(size_t)h * CL + c];
    float av = accA[r], bv = accB[r];
    ob[(size_t)h * CL + c] = cv;
    ob[(size_t)(H + h) * CL + c] = av;
    ob[(size_t)(2 * H + h) * CL + c] = cv * av;
    ob[(size_t)(3 * H + h) * CL + c] = cv * bv;
  }
}

extern "C" void kernel_launch(void* const* d_in, const int* in_sizes, int n_in,
                              void* d_out, int out_size, void* d_ws, size_t ws_size,
                              hipStream_t stream) {
  const float* context  = (const float*)d_in[0];
  const float* question = (const float*)d_in[1];
  const int*   c_mask   = (const int*)d_in[2];
  const int*   q_mask   = (const int*)d_in[3];
  const float* w        = (const float*)d_in[4];
  float* out = (float*)d_out;

  char* ws = (char*)d_ws;
  size_t off = 0;
  auto alloc = [&](size_t bytes) -> void* {
    void* p = ws + off;
    off += (bytes + 255) & ~(size_t)255;
    return p;
  };
  float* s_buf = (float*)alloc((size_t)B * CL * QL * sizeof(float));            // 33.5 MB
  unsigned short* s1_bf = (unsigned short*)alloc((size_t)B * CL * QL * 2);      // 16.8 MB
  unsigned short* s2_bf = (unsigned short*)alloc((size_t)B * QL * CL * 2);      // 16.8 MB
  unsigned short* ctx_bf = (unsigned short*)alloc((size_t)B * H * CL * 2);      // 8.4 MB
  unsigned short* qry_bf = (unsigned short*)alloc((size_t)B * H * QL * 2);      // 1.05 MB
  unsigned short* tT_bf = (unsigned short*)alloc((size_t)B * H * QL * 2);       // 1.05 MB
  float* cterm = (float*)alloc((size_t)B * CL * sizeof(float));
  float* qterm = (float*)alloc((size_t)B * QL * sizeof(float));
  float* cmax_ = (float*)alloc((size_t)B * QL * sizeof(float));
  float* cinv_ = (float*)alloc((size_t)B * QL * sizeof(float));
  float* pmax_ = (float*)alloc((size_t)B * K4N * QL * sizeof(float));
  float* psum_ = (float*)alloc((size_t)B * K4N * QL * sizeof(float));
  // tpart aliases s_buf: s is dead once kexp2 completes (stream-ordered before k5)
  float* tpart = s_buf;  // needs 16.8 MB < 33.5 MB

  kprep<<<dim3(2048), dim3(256), 0, stream>>>(context, question, ctx_bf, qry_bf);

  k1_bias<<<dim3((B * CL + B * QL + 255) / 256), dim3(256), 0, stream>>>(
      context, question, w, cterm, qterm);

  k2_score<<<dim3(QL / 64, CL / 64, B), dim3(256), 0, stream>>>(
      context, question, w, cterm, qterm, s_buf);

  k3_rowstats<<<dim3(B * CL / 4), dim3(256), 0, stream>>>(
      s_buf, q_mask, s1_bf);

  k4a_colpart<<<dim3(K4N, B), dim3(256), 0, stream>>>(
      s_buf, c_mask, pmax_, psum_);

  k4b_colreduce<<<dim3((B * QL + 255) / 256), dim3(256), 0, stream>>>(
      pmax_, psum_, cmax_, cinv_);

  kexp2<<<dim3(CL / 32, B), dim3(256), 0, stream>>>(
      s_buf, c_mask, cmax_, cinv_, s2_bf);

  k5_tpart<<<dim3(QL / 32, SPLITK5, B), dim3(256), 0, stream>>>(
      s2_bf, ctx_bf, tpart);

  k5b_treduce<<<dim3(QL / 64, B), dim3(256), 0, stream>>>(
      tpart, tT_bf);

  k6_out<<<dim3(CL / 32, B), dim3(256), 0, stream>>>(
      s1_bf, qry_bf, tT_bf, context, out);
}

// Round 4
// 142.182 us; speedup vs baseline: 2.9056x; 1.1148x over previous
//
#include <hip/hip_runtime.h>

typedef short bf16x8 __attribute__((ext_vector_type(8)));   // 8 bf16 = 4 VGPRs
typedef float f32x16 __attribute__((ext_vector_type(16)));  // MFMA 32x32 acc

constexpr int B  = 16;
constexpr int H  = 128;
constexpr int CL = 2048;
constexpr int QL = 256;
constexpr int SPLITK5 = 8;
constexpr int K5SEG = CL / SPLITK5;   // 256
constexpr float NEG = -1e30f;
constexpr float SHIFT = 8.0f;         // column-exp shift (|s| << 88+8, overflow-safe)

__device__ __forceinline__ unsigned short f2bf(float x) {
  unsigned u = __float_as_uint(x);
  u += 0x7fffu + ((u >> 16) & 1u);   // round-to-nearest-even
  return (unsigned short)(u >> 16);
}

// ---------------- KT: fp32 -> bf16 linear + (scaled) transposed copies + bias partials ----
// grid (L/64, H/64, B), block 256.
template<int L, bool SCALE>
__global__ __launch_bounds__(256) void ktrans(
    const float* __restrict__ src, const float* __restrict__ wbias,
    const float* __restrict__ wscale,
    unsigned short* __restrict__ dlin, unsigned short* __restrict__ dT,
    float* __restrict__ pbias) {
  __shared__ unsigned short T[64][72];
  __shared__ float P[16][64];
  const int c0 = blockIdx.x * 64;
  const int h1 = blockIdx.y;
  const int b  = blockIdx.z;
  const int tid = threadIdx.x;
  const int hh = tid >> 4;
  const int cc4 = (tid & 15) * 4;
  float4 part = make_float4(0.f, 0.f, 0.f, 0.f);
  #pragma unroll
  for (int it = 0; it < 4; ++it) {
    const int hrow = it * 16 + hh;
    const int h = h1 * 64 + hrow;
    float4 v = *(const float4*)&src[((size_t)b * H + h) * L + c0 + cc4];
    const float wb = wbias[h];
    part.x = fmaf(v.x, wb, part.x); part.y = fmaf(v.y, wb, part.y);
    part.z = fmaf(v.z, wb, part.z); part.w = fmaf(v.w, wb, part.w);
    ushort4 o;
    o.x = f2bf(v.x); o.y = f2bf(v.y); o.z = f2bf(v.z); o.w = f2bf(v.w);
    *(ushort4*)&dlin[((size_t)b * H + h) * L + c0 + cc4] = o;
    ushort4 ot;
    if (SCALE) {
      const float ws = wscale[h];
      ot.x = f2bf(v.x * ws); ot.y = f2bf(v.y * ws);
      ot.z = f2bf(v.z * ws); ot.w = f2bf(v.w * ws);
    } else {
      ot = o;
    }
    *(ushort4*)&T[hrow][cc4] = ot;
  }
  *(float4*)&P[hh][cc4] = part;
  __syncthreads();
  if (tid < 64) {
    float sum = 0.f;
    #pragma unroll
    for (int i = 0; i < 16; ++i) sum += P[i][tid];
    pbias[(size_t)h1 * B * L + (size_t)b * L + c0 + tid] = sum;
  }
  #pragma unroll
  for (int it = 0; it < 4; ++it) {
    int lin = it * 256 + tid;
    int c = lin >> 4, hc = (lin & 15) * 4;
    ushort4 o;
    o.x = T[hc + 0][c]; o.y = T[hc + 1][c];
    o.z = T[hc + 2][c]; o.w = T[hc + 3][c];
    *(ushort4*)&dT[((size_t)b * L + c0 + c) * H + h1 * 64 + hc] = o;
  }
}

// ---------------- KR: combine 2 h-tile partials -> cterm, qterm ----------------
__global__ __launch_bounds__(256) void kreduce(
    const float* __restrict__ pct, const float* __restrict__ pqt,
    float* __restrict__ cterm, float* __restrict__ qterm) {
  int idx = blockIdx.x * 256 + threadIdx.x;
  if (idx < B * CL) {
    cterm[idx] = pct[idx] + pct[B * CL + idx];
  } else if (idx < B * CL + B * QL) {
    int i2 = idx - B * CL;
    qterm[i2] = pqt[i2] + pqt[B * QL + i2];
  }
}

// ---------------- K2F: MFMA score + fused row softmax + column exp ----------------
// grid (CL/32, B), block 512 (8 waves; wave w = q-tile w).
// Writes s1_bf[c][q] (row-softmaxed), s2u[q][c] = exp(s-SHIFT), Lpart (col partial sums).
__global__ __launch_bounds__(512) void k2_fused(
    const unsigned short* __restrict__ ctxwT, const unsigned short* __restrict__ qryT,
    const float* __restrict__ cterm, const float* __restrict__ qterm,
    const int* __restrict__ cmask, const int* __restrict__ qmask,
    unsigned short* __restrict__ s1bf, unsigned short* __restrict__ s2u,
    float* __restrict__ Lpart) {
  __shared__ float stat[32][9];
  __shared__ unsigned short tile[10240];   // reused: S1 [32][264], then S2 [256][40]
  const int cblk = blockIdx.x;
  const int c0 = cblk * 32;
  const int b = blockIdx.y;
  const int tid = threadIdx.x;
  const int w = tid >> 6;
  const int l = tid & 63;
  const int lr = l & 31, lg = l >> 5;
  const int q0 = w * 32;
  const int q = q0 + lr;

  // MFMA: M=c(32), N=q(32), K=H=128. Direct global fragments.
  const unsigned short* ap = ctxwT + ((size_t)b * CL + c0 + lr) * H + lg * 8;
  const unsigned short* bp = qryT + ((size_t)b * QL + q) * H + lg * 8;
  f32x16 acc = {};
  #pragma unroll
  for (int k = 0; k < H; k += 16) {
    bf16x8 af = *(const bf16x8*)(ap + k);
    bf16x8 bf_ = *(const bf16x8*)(bp + k);
    acc = __builtin_amdgcn_mfma_f32_32x32x16_bf16(af, bf_, acc, 0, 0, 0);
  }

  const float qt = qterm[b * QL + q];
  const int qm = qmask[b * QL + q];
  float s[16];
  unsigned cmbits = 0;
  #pragma unroll
  for (int r = 0; r < 16; ++r) {
    const int cr = (r & 3) + 8 * (r >> 2) + 4 * lg;
    s[r] = acc[r] + cterm[b * CL + c0 + cr] + qt;
    cmbits |= (cmask[b * CL + c0 + cr] > 0 ? 1u : 0u) << r;
  }

  // ---- row softmax over q (per c-row): wave-local shfl reduce + LDS cross-wave ----
  #pragma unroll
  for (int r = 0; r < 16; ++r) {
    float m = qm > 0 ? s[r] : NEG;
    m = fmaxf(m, __shfl_xor(m, 1));  m = fmaxf(m, __shfl_xor(m, 2));
    m = fmaxf(m, __shfl_xor(m, 4));  m = fmaxf(m, __shfl_xor(m, 8));
    m = fmaxf(m, __shfl_xor(m, 16));
    if (lr == 0) stat[(r & 3) + 8 * (r >> 2) + 4 * lg][w] = m;
  }
  __syncthreads();
  float gmax[16];
  #pragma unroll
  for (int r = 0; r < 16; ++r) {
    const int cr = (r & 3) + 8 * (r >> 2) + 4 * lg;
    float m = stat[cr][0];
    #pragma unroll
    for (int ww = 1; ww < 8; ++ww) m = fmaxf(m, stat[cr][ww]);
    gmax[r] = m;
  }
  __syncthreads();
  float e[16];
  #pragma unroll
  for (int r = 0; r < 16; ++r) {
    const float x = qm > 0 ? s[r] : NEG;
    e[r] = expf(x - gmax[r]);
    float sm = e[r];
    sm += __shfl_xor(sm, 1);  sm += __shfl_xor(sm, 2);
    sm += __shfl_xor(sm, 4);  sm += __shfl_xor(sm, 8);
    sm += __shfl_xor(sm, 16);
    if (lr == 0) stat[(r & 3) + 8 * (r >> 2) + 4 * lg][w] = sm;
  }
  __syncthreads();
  // write s1 into LDS tile [32 c][264]
  #pragma unroll
  for (int r = 0; r < 16; ++r) {
    const int cr = (r & 3) + 8 * (r >> 2) + 4 * lg;
    float sum = stat[cr][0];
    #pragma unroll
    for (int ww = 1; ww < 8; ++ww) sum += stat[cr][ww];
    tile[cr * 264 + q] = f2bf(e[r] / sum);
  }
  __syncthreads();
  {  // copy out s1: 32 c x 256 q
    const int c = tid >> 4, qo = (tid & 15) * 16;
    bf16x8 v0 = *(const bf16x8*)&tile[c * 264 + qo];
    bf16x8 v1 = *(const bf16x8*)&tile[c * 264 + qo + 8];
    unsigned short* op = s1bf + ((size_t)b * CL + c0 + c) * QL + qo;
    *(bf16x8*)op = v0;
    *(bf16x8*)(op + 8) = v1;
  }
  __syncthreads();

  // ---- column path: e2 = exp(s - SHIFT), partial col sums, store transposed ----
  float csum = 0.f;
  #pragma unroll
  for (int r = 0; r < 16; ++r) {
    const int cr = (r & 3) + 8 * (r >> 2) + 4 * lg;
    const float x = (cmbits >> r) & 1u ? s[r] : NEG;
    const float e2 = expf(x - SHIFT);
    csum += e2;
    tile[q * 40 + cr] = f2bf(e2);
  }
  csum += __shfl_xor(csum, 32);
  if (lg == 0) Lpart[((size_t)b * 64 + cblk) * QL + q] = csum;
  __syncthreads();
  {  // copy out s2u: 256 q x 32 c
    const int qq = tid >> 1, co = (tid & 1) * 16;
    bf16x8 v0 = *(const bf16x8*)&tile[qq * 40 + co];
    bf16x8 v1 = *(const bf16x8*)&tile[qq * 40 + co + 8];
    unsigned short* op = s2u + ((size_t)b * QL + qq) * CL + c0 + co;
    *(bf16x8*)op = v0;
    *(bf16x8*)(op + 8) = v1;
  }
}

// ---------------- KL: cinv[b][q] = 1 / sum_cblk Lpart ----------------
__global__ __launch_bounds__(256) void kLred(
    const float* __restrict__ Lpart, float* __restrict__ cinv) {
  int idx = blockIdx.x * 256 + threadIdx.x;
  if (idx >= B * QL) return;
  int b = idx >> 8, q = idx & 255;
  float L = 0.f;
  #pragma unroll 8
  for (int cb = 0; cb < 64; ++cb) L += Lpart[((size_t)b * 64 + cb) * QL + q];
  cinv[idx] = 1.0f / L;
}

// ---------------- K5: MFMA tpart[seg][b][q][h] = sum_{c in seg} s2u[q,c]*ctx[h,c] ---
__global__ __launch_bounds__(256) void k5_tpart(
    const unsigned short* __restrict__ s2u,
    const unsigned short* __restrict__ ctxbf,
    float* __restrict__ tpart) {
  const int q0 = blockIdx.x * 32;
  const int seg = blockIdx.y;
  const int b = blockIdx.z;
  const int w = threadIdx.x >> 6, l = threadIdx.x & 63;
  const int h0 = w * 32;
  const int lr = l & 31, lg = l >> 5;
  const unsigned short* ap = s2u + ((size_t)b * QL + q0 + lr) * CL + seg * K5SEG + lg * 8;
  const unsigned short* bp = ctxbf + ((size_t)b * H + h0 + lr) * CL + seg * K5SEG + lg * 8;
  f32x16 acc = {};
  #pragma unroll
  for (int k = 0; k < K5SEG; k += 16) {
    bf16x8 af = *(const bf16x8*)(ap + k);
    bf16x8 bfr = *(const bf16x8*)(bp + k);
    acc = __builtin_amdgcn_mfma_f32_32x32x16_bf16(af, bfr, acc, 0, 0, 0);
  }
  float* tp = tpart + (size_t)(seg * B + b) * QL * H;
  #pragma unroll
  for (int r = 0; r < 16; ++r) {
    int qrow = (r & 3) + 8 * (r >> 2) + 4 * lg;
    tp[(size_t)(q0 + qrow) * H + h0 + lr] = acc[r];
  }
}

// ---------------- K5b: reduce tpart over segs, scale by cinv, write tT_bf[b][h][q] ---
__global__ __launch_bounds__(256) void k5b_treduce(
    const float* __restrict__ tpart, const float* __restrict__ cinv,
    unsigned short* __restrict__ tTbf) {
  __shared__ unsigned short lds[128 * 66];
  const int q0 = blockIdx.x * 64, b = blockIdx.y;
  const int tid = threadIdx.x;
  for (int lin = tid; lin < 64 * 128; lin += 256) {
    int q = lin >> 7, h = lin & 127;
    float v = 0.f;
    #pragma unroll
    for (int sgt = 0; sgt < SPLITK5; ++sgt)
      v += tpart[((size_t)(sgt * B + b) * QL + q0 + q) * H + h];
    lds[h * 66 + q] = f2bf(v * cinv[b * QL + q0 + q]);
  }
  __syncthreads();
  for (int lin = tid; lin < 64 * 128; lin += 256) {
    int h = lin >> 6, q = lin & 63;
    tTbf[((size_t)b * H + h) * QL + q0 + q] = lds[h * 66 + q];
  }
}

// ---------------- K6: MFMA dual-GEMM + fused output ----------------
__global__ __launch_bounds__(256) void k6_out(
    const unsigned short* __restrict__ s1bf,
    const unsigned short* __restrict__ qrybf,
    const unsigned short* __restrict__ tTbf,
    const float* __restrict__ ctx, float* __restrict__ out) {
  const int c0 = blockIdx.x * 32;
  const int b = blockIdx.y;
  const int w = threadIdx.x >> 6, l = threadIdx.x & 63;
  const int h0 = w * 32;
  const int lr = l & 31, lg = l >> 5;
  const unsigned short* bp  = s1bf  + ((size_t)b * CL + c0 + lr) * QL + lg * 8;
  const unsigned short* a1p = qrybf + ((size_t)b * H  + h0 + lr) * QL + lg * 8;
  const unsigned short* a2p = tTbf  + ((size_t)b * H  + h0 + lr) * QL + lg * 8;
  f32x16 accA = {}, accB = {};
  #pragma unroll
  for (int k = 0; k < QL; k += 16) {
    bf16x8 bfr = *(const bf16x8*)(bp + k);
    bf16x8 a1 = *(const bf16x8*)(a1p + k);
    bf16x8 a2 = *(const bf16x8*)(a2p + k);
    accA = __builtin_amdgcn_mfma_f32_32x32x16_bf16(a1, bfr, accA, 0, 0, 0);
    accB = __builtin_amdgcn_mfma_f32_32x32x16_bf16(a2, bfr, accB, 0, 0, 0);
  }
  const float* cb = ctx + (size_t)b * H * CL;
  float* ob = out + (size_t)b * 4 * H * CL;
  #pragma unroll
  for (int r = 0; r < 16; ++r) {
    int h = h0 + (r & 3) + 8 * (r >> 2) + 4 * lg;
    int c = c0 + lr;
    float cv = cb[(size_t)h * CL + c];
    float av = accA[r], bv = accB[r];
    ob[(size_t)h * CL + c] = cv;
    ob[(size_t)(H + h) * CL + c] = av;
    ob[(size_t)(2 * H + h) * CL + c] = cv * av;
    ob[(size_t)(3 * H + h) * CL + c] = cv * bv;
  }
}

extern "C" void kernel_launch(void* const* d_in, const int* in_sizes, int n_in,
                              void* d_out, int out_size, void* d_ws, size_t ws_size,
                              hipStream_t stream) {
  const float* context  = (const float*)d_in[0];
  const float* question = (const float*)d_in[1];
  const int*   c_mask   = (const int*)d_in[2];
  const int*   q_mask   = (const int*)d_in[3];
  const float* w        = (const float*)d_in[4];
  float* out = (float*)d_out;

  char* ws = (char*)d_ws;
  size_t off = 0;
  auto alloc = [&](size_t bytes) -> void* {
    void* p = ws + off;
    off += (bytes + 255) & ~(size_t)255;
    return p;
  };
  unsigned short* ctx_bf = (unsigned short*)alloc((size_t)B * H * CL * 2);   // 8.4 MB
  unsigned short* ctxwT  = (unsigned short*)alloc((size_t)B * CL * H * 2);   // 8.4 MB
  unsigned short* qry_bf = (unsigned short*)alloc((size_t)B * H * QL * 2);   // 1.05 MB
  unsigned short* qryT   = (unsigned short*)alloc((size_t)B * QL * H * 2);   // 1.05 MB
  unsigned short* s1_bf  = (unsigned short*)alloc((size_t)B * CL * QL * 2);  // 16.8 MB
  unsigned short* s2u    = (unsigned short*)alloc((size_t)B * QL * CL * 2);  // 16.8 MB
  float* tpart = (float*)alloc((size_t)SPLITK5 * B * QL * H * sizeof(float)); // 16.8 MB
  unsigned short* tT_bf  = (unsigned short*)alloc((size_t)B * H * QL * 2);   // 1.05 MB
  float* pcterm = (float*)alloc((size_t)2 * B * CL * sizeof(float));
  float* pqterm = (float*)alloc((size_t)2 * B * QL * sizeof(float));
  float* cterm  = (float*)alloc((size_t)B * CL * sizeof(float));
  float* qterm  = (float*)alloc((size_t)B * QL * sizeof(float));
  float* Lpart  = (float*)alloc((size_t)B * 64 * QL * sizeof(float));        // 1 MB
  float* cinv_  = (float*)alloc((size_t)B * QL * sizeof(float));

  ktrans<CL, true><<<dim3(CL / 64, H / 64, B), dim3(256), 0, stream>>>(
      context, w + H, w + 2 * H, ctx_bf, ctxwT, pcterm);

  ktrans<QL, false><<<dim3(QL / 64, H / 64, B), dim3(256), 0, stream>>>(
      question, w, w, qry_bf, qryT, pqterm);

  kreduce<<<dim3((B * CL + B * QL + 255) / 256), dim3(256), 0, stream>>>(
      pcterm, pqterm, cterm, qterm);

  k2_fused<<<dim3(CL / 32, B), dim3(512), 0, stream>>>(
      ctxwT, qryT, cterm, qterm, c_mask, q_mask, s1_bf, s2u, Lpart);

  kLred<<<dim3((B * QL + 255) / 256), dim3(256), 0, stream>>>(Lpart, cinv_);

  k5_tpart<<<dim3(QL / 32, SPLITK5, B), dim3(256), 0, stream>>>(
      s2u, ctx_bf, tpart);

  k5b_treduce<<<dim3(QL / 64, B), dim3(256), 0, stream>>>(
      tpart, cinv_, tT_bf);

  k6_out<<<dim3(CL / 32, B), dim3(256), 0, stream>>>(
      s1_bf, qry_bf, tT_bf, context, out);
}

// Round 5
// 105.337 us; speedup vs baseline: 3.9218x; 1.3498x over previous
//
#include <hip/hip_runtime.h>

typedef short bf16x8 __attribute__((ext_vector_type(8)));   // 8 bf16 = 4 VGPRs
typedef float f32x16 __attribute__((ext_vector_type(16)));  // MFMA 32x32 acc

constexpr int B  = 16;
constexpr int H  = 128;
constexpr int CL = 2048;
constexpr int QL = 256;
constexpr int SPLITK5 = 8;
constexpr int K5SEG = CL / SPLITK5;   // 256
constexpr float NEG = -1e30f;
constexpr float SHIFT = 8.0f;         // column-exp shift (overflow-safe for |s|~O(10))

__device__ __forceinline__ unsigned short f2bf(float x) {
  unsigned u = __float_as_uint(x);
  u += 0x7fffu + ((u >> 16) & 1u);   // round-to-nearest-even
  return (unsigned short)(u >> 16);
}

// ---------------- KT: fp32 -> bf16 linear + (scaled) transposed copies + bias partials ----
template<int L, bool SCALE>
__global__ __launch_bounds__(256) void ktrans(
    const float* __restrict__ src, const float* __restrict__ wbias,
    const float* __restrict__ wscale,
    unsigned short* __restrict__ dlin, unsigned short* __restrict__ dT,
    float* __restrict__ pbias) {
  __shared__ unsigned short T[64][72];
  __shared__ float P[16][64];
  const int c0 = blockIdx.x * 64;
  const int h1 = blockIdx.y;
  const int b  = blockIdx.z;
  const int tid = threadIdx.x;
  const int hh = tid >> 4;
  const int cc4 = (tid & 15) * 4;
  float4 part = make_float4(0.f, 0.f, 0.f, 0.f);
  #pragma unroll
  for (int it = 0; it < 4; ++it) {
    const int hrow = it * 16 + hh;
    const int h = h1 * 64 + hrow;
    float4 v = *(const float4*)&src[((size_t)b * H + h) * L + c0 + cc4];
    const float wb = wbias[h];
    part.x = fmaf(v.x, wb, part.x); part.y = fmaf(v.y, wb, part.y);
    part.z = fmaf(v.z, wb, part.z); part.w = fmaf(v.w, wb, part.w);
    ushort4 o;
    o.x = f2bf(v.x); o.y = f2bf(v.y); o.z = f2bf(v.z); o.w = f2bf(v.w);
    *(ushort4*)&dlin[((size_t)b * H + h) * L + c0 + cc4] = o;
    ushort4 ot;
    if (SCALE) {
      const float ws = wscale[h];
      ot.x = f2bf(v.x * ws); ot.y = f2bf(v.y * ws);
      ot.z = f2bf(v.z * ws); ot.w = f2bf(v.w * ws);
    } else {
      ot = o;
    }
    *(ushort4*)&T[hrow][cc4] = ot;
  }
  *(float4*)&P[hh][cc4] = part;
  __syncthreads();
  if (tid < 64) {
    float sum = 0.f;
    #pragma unroll
    for (int i = 0; i < 16; ++i) sum += P[i][tid];
    pbias[(size_t)h1 * B * L + (size_t)b * L + c0 + tid] = sum;
  }
  #pragma unroll
  for (int it = 0; it < 4; ++it) {
    int lin = it * 256 + tid;
    int c = lin >> 4, hc = (lin & 15) * 4;
    ushort4 o;
    o.x = T[hc + 0][c]; o.y = T[hc + 1][c];
    o.z = T[hc + 2][c]; o.w = T[hc + 3][c];
    *(ushort4*)&dT[((size_t)b * L + c0 + c) * H + h1 * 64 + hc] = o;
  }
}

// ---------------- KR: combine 2 h-tile partials -> cterm, qterm ----------------
__global__ __launch_bounds__(256) void kreduce(
    const float* __restrict__ pct, const float* __restrict__ pqt,
    float* __restrict__ cterm, float* __restrict__ qterm) {
  int idx = blockIdx.x * 256 + threadIdx.x;
  if (idx < B * CL) {
    cterm[idx] = pct[idx] + pct[B * CL + idx];
  } else if (idx < B * CL + B * QL) {
    int i2 = idx - B * CL;
    qterm[i2] = pqt[i2] + pqt[B * QL + i2];
  }
}

// ---------------- K2F: MFMA score (M=q, N=c) + fused row softmax + column exp ----
// grid (CL/32, B), block 512 (8 waves; wave w owns q-tile w).
// Lane owns column c = c0+(l&31); regs own 16 q-rows -> row softmax mostly in-register.
__global__ __launch_bounds__(512) void k2_fused(
    const unsigned short* __restrict__ ctxwT, const unsigned short* __restrict__ qryT,
    const float* __restrict__ cterm, const float* __restrict__ qterm,
    const int* __restrict__ cmask, const int* __restrict__ qmask,
    unsigned short* __restrict__ s1bf, unsigned short* __restrict__ s2u,
    float* __restrict__ Lpart) {
  __shared__ float statm[32][9];
  __shared__ float stats[32][9];
  __shared__ unsigned short tile[10240];   // s1: [32 c][264 q]; s2: [256 q][40 c]
  const int cblk = blockIdx.x;
  const int c0 = cblk * 32;
  const int b = blockIdx.y;
  const int tid = threadIdx.x;
  const int w = tid >> 6;
  const int l = tid & 63;
  const int lr = l & 31, hi = l >> 5;
  const int q0 = w * 32;
  const int c = c0 + lr;

  // MFMA: A = qryT rows (M=q), B = ctxwT rows (N=c), K=H=128, direct global frags.
  const unsigned short* ap = qryT + ((size_t)b * QL + q0 + lr) * H + hi * 8;
  const unsigned short* bp = ctxwT + ((size_t)b * CL + c) * H + hi * 8;
  f32x16 acc = {};
  #pragma unroll
  for (int k = 0; k < H; k += 16) {
    bf16x8 af = *(const bf16x8*)(ap + k);
    bf16x8 bf_ = *(const bf16x8*)(bp + k);
    acc = __builtin_amdgcn_mfma_f32_32x32x16_bf16(af, bf_, acc, 0, 0, 0);
  }

  const float ct = cterm[b * CL + c];
  const bool cm = cmask[b * CL + c] > 0;
  float s[16], qt[16];
  unsigned qmb = 0;
  #pragma unroll
  for (int g = 0; g < 4; ++g) {
    const int qbase = q0 + 4 * hi + 8 * g;
    float4 q4 = *(const float4*)&qterm[b * QL + qbase];
    int4 m4 = *(const int4*)&qmask[b * QL + qbase];
    qt[4 * g + 0] = q4.x; qt[4 * g + 1] = q4.y;
    qt[4 * g + 2] = q4.z; qt[4 * g + 3] = q4.w;
    qmb |= (m4.x > 0 ? 1u : 0u) << (4 * g + 0);
    qmb |= (m4.y > 0 ? 1u : 0u) << (4 * g + 1);
    qmb |= (m4.z > 0 ? 1u : 0u) << (4 * g + 2);
    qmb |= (m4.w > 0 ? 1u : 0u) << (4 * g + 3);
  }
  #pragma unroll
  for (int r = 0; r < 16; ++r) s[r] = acc[r] + ct + qt[r];

  // ---- row softmax over q, per column c: in-reg + 1 shfl + 8-wide LDS combine ----
  float e[16];
  float m = NEG;
  #pragma unroll
  for (int r = 0; r < 16; ++r) {
    e[r] = ((qmb >> r) & 1u) ? s[r] : NEG;
    m = fmaxf(m, e[r]);
  }
  m = fmaxf(m, __shfl_xor(m, 32));
  if (hi == 0) statm[lr][w] = m;
  __syncthreads();
  float gmax = statm[lr][0];
  #pragma unroll
  for (int ww = 1; ww < 8; ++ww) gmax = fmaxf(gmax, statm[lr][ww]);
  float sm = 0.f;
  #pragma unroll
  for (int r = 0; r < 16; ++r) { e[r] = __expf(e[r] - gmax); sm += e[r]; }
  sm += __shfl_xor(sm, 32);
  if (hi == 0) stats[lr][w] = sm;
  __syncthreads();
  float rsum = stats[lr][0];
  #pragma unroll
  for (int ww = 1; ww < 8; ++ww) rsum += stats[lr][ww];
  const float rinv = 1.0f / rsum;

  // s1 tile [32 c][264 q]; per-reg-group q's are contiguous -> b64 writes
  #pragma unroll
  for (int g = 0; g < 4; ++g) {
    ushort4 o;
    o.x = f2bf(e[4 * g + 0] * rinv); o.y = f2bf(e[4 * g + 1] * rinv);
    o.z = f2bf(e[4 * g + 2] * rinv); o.w = f2bf(e[4 * g + 3] * rinv);
    *(ushort4*)&tile[lr * 264 + q0 + 4 * hi + 8 * g] = o;
  }
  __syncthreads();
  {  // coalesced s1 copy-out: 32 c x 256 q
    const int cr = tid >> 4, qo = (tid & 15) * 16;
    bf16x8 v0 = *(const bf16x8*)&tile[cr * 264 + qo];
    bf16x8 v1 = *(const bf16x8*)&tile[cr * 264 + qo + 8];
    unsigned short* op = s1bf + ((size_t)b * CL + c0 + cr) * QL + qo;
    *(bf16x8*)op = v0;
    *(bf16x8*)(op + 8) = v1;
  }
  __syncthreads();

  // ---- column path: e2 = exp(s - SHIFT) (raw s, cmask only) ----
  #pragma unroll
  for (int r = 0; r < 16; ++r) {
    const float e2 = cm ? __expf(s[r] - SHIFT) : 0.f;
    tile[(q0 + (r & 3) + 8 * (r >> 2) + 4 * hi) * 40 + lr] = f2bf(e2);
  }
  __syncthreads();
  {  // coalesced s2u copy-out + fused column partial sums
    const int q = tid >> 1, co = (tid & 1) * 16;
    bf16x8 v0 = *(const bf16x8*)&tile[q * 40 + co];
    bf16x8 v1 = *(const bf16x8*)&tile[q * 40 + co + 8];
    float cs = 0.f;
    #pragma unroll
    for (int i2 = 0; i2 < 8; ++i2) {
      cs += __uint_as_float((unsigned)(unsigned short)v0[i2] << 16);
      cs += __uint_as_float((unsigned)(unsigned short)v1[i2] << 16);
    }
    cs += __shfl_xor(cs, 1);
    unsigned short* op = s2u + ((size_t)b * QL + q) * CL + c0 + co;
    *(bf16x8*)op = v0;
    *(bf16x8*)(op + 8) = v1;
    if ((tid & 1) == 0) Lpart[((size_t)b * 64 + cblk) * QL + q] = cs;
  }
}

// ---------------- KL: cinv[b][q] = 1 / sum_cblk Lpart ----------------
__global__ __launch_bounds__(256) void kLred(
    const float* __restrict__ Lpart, float* __restrict__ cinv) {
  int idx = blockIdx.x * 256 + threadIdx.x;
  if (idx >= B * QL) return;
  int b = idx >> 8, q = idx & 255;
  float L = 0.f;
  #pragma unroll 8
  for (int cb = 0; cb < 64; ++cb) L += Lpart[((size_t)b * 64 + cb) * QL + q];
  cinv[idx] = 1.0f / L;
}

// ---------------- K5: MFMA tpart[seg][b][q][h] = sum_{c in seg} s2u[q,c]*ctx[h,c] ---
__global__ __launch_bounds__(256) void k5_tpart(
    const unsigned short* __restrict__ s2u,
    const unsigned short* __restrict__ ctxbf,
    float* __restrict__ tpart) {
  const int q0 = blockIdx.x * 32;
  const int seg = blockIdx.y;
  const int b = blockIdx.z;
  const int w = threadIdx.x >> 6, l = threadIdx.x & 63;
  const int h0 = w * 32;
  const int lr = l & 31, lg = l >> 5;
  const unsigned short* ap = s2u + ((size_t)b * QL + q0 + lr) * CL + seg * K5SEG + lg * 8;
  const unsigned short* bp = ctxbf + ((size_t)b * H + h0 + lr) * CL + seg * K5SEG + lg * 8;
  f32x16 acc = {};
  #pragma unroll
  for (int k = 0; k < K5SEG; k += 16) {
    bf16x8 af = *(const bf16x8*)(ap + k);
    bf16x8 bfr = *(const bf16x8*)(bp + k);
    acc = __builtin_amdgcn_mfma_f32_32x32x16_bf16(af, bfr, acc, 0, 0, 0);
  }
  float* tp = tpart + (size_t)(seg * B + b) * QL * H;
  #pragma unroll
  for (int r = 0; r < 16; ++r) {
    int qrow = (r & 3) + 8 * (r >> 2) + 4 * lg;
    tp[(size_t)(q0 + qrow) * H + h0 + lr] = acc[r];
  }
}

// ---------------- K5b: reduce tpart over segs, scale by cinv, write tT_bf[b][h][q] ---
__global__ __launch_bounds__(256) void k5b_treduce(
    const float* __restrict__ tpart, const float* __restrict__ cinv,
    unsigned short* __restrict__ tTbf) {
  __shared__ unsigned short lds[128 * 66];
  const int q0 = blockIdx.x * 64, b = blockIdx.y;
  const int tid = threadIdx.x;
  for (int lin = tid; lin < 64 * 128; lin += 256) {
    int q = lin >> 7, h = lin & 127;
    float v = 0.f;
    #pragma unroll
    for (int sgt = 0; sgt < SPLITK5; ++sgt)
      v += tpart[((size_t)(sgt * B + b) * QL + q0 + q) * H + h];
    lds[h * 66 + q] = f2bf(v * cinv[b * QL + q0 + q]);
  }
  __syncthreads();
  for (int lin = tid; lin < 64 * 128; lin += 256) {
    int h = lin >> 6, q = lin & 63;
    tTbf[((size_t)b * H + h) * QL + q0 + q] = lds[h * 66 + q];
  }
}

// ---------------- K6: MFMA dual-GEMM + fused output ----------------
__global__ __launch_bounds__(256) void k6_out(
    const unsigned short* __restrict__ s1bf,
    const unsigned short* __restrict__ qrybf,
    const unsigned short* __restrict__ tTbf,
    const float* __restrict__ ctx, float* __restrict__ out) {
  const int c0 = blockIdx.x * 32;
  const int b = blockIdx.y;
  const int w = threadIdx.x >> 6, l = threadIdx.x & 63;
  const int h0 = w * 32;
  const int lr = l & 31, lg = l >> 5;
  const unsigned short* bp  = s1bf  + ((size_t)b * CL + c0 + lr) * QL + lg * 8;
  const unsigned short* a1p = qrybf + ((size_t)b * H  + h0 + lr) * QL + lg * 8;
  const unsigned short* a2p = tTbf  + ((size_t)b * H  + h0 + lr) * QL + lg * 8;
  f32x16 accA = {}, accB = {};
  #pragma unroll
  for (int k = 0; k < QL; k += 16) {
    bf16x8 bfr = *(const bf16x8*)(bp + k);
    bf16x8 a1 = *(const bf16x8*)(a1p + k);
    bf16x8 a2 = *(const bf16x8*)(a2p + k);
    accA = __builtin_amdgcn_mfma_f32_32x32x16_bf16(a1, bfr, accA, 0, 0, 0);
    accB = __builtin_amdgcn_mfma_f32_32x32x16_bf16(a2, bfr, accB, 0, 0, 0);
  }
  const float* cb = ctx + (size_t)b * H * CL;
  float* ob = out + (size_t)b * 4 * H * CL;
  #pragma unroll
  for (int r = 0; r < 16; ++r) {
    int h = h0 + (r & 3) + 8 * (r >> 2) + 4 * lg;
    int c = c0 + lr;
    float cv = cb[(size_t)h * CL + c];
    float av = accA[r], bv = accB[r];
    ob[(size_t)h * CL + c] = cv;
    ob[(size_t)(H + h) * CL + c] = av;
    ob[(size_t)(2 * H + h) * CL + c] = cv * av;
    ob[(size_t)(3 * H + h) * CL + c] = cv * bv;
  }
}

extern "C" void kernel_launch(void* const* d_in, const int* in_sizes, int n_in,
                              void* d_out, int out_size, void* d_ws, size_t ws_size,
                              hipStream_t stream) {
  const float* context  = (const float*)d_in[0];
  const float* question = (const float*)d_in[1];
  const int*   c_mask   = (const int*)d_in[2];
  const int*   q_mask   = (const int*)d_in[3];
  const float* w        = (const float*)d_in[4];
  float* out = (float*)d_out;

  char* ws = (char*)d_ws;
  size_t off = 0;
  auto alloc = [&](size_t bytes) -> void* {
    void* p = ws + off;
    off += (bytes + 255) & ~(size_t)255;
    return p;
  };
  unsigned short* ctx_bf = (unsigned short*)alloc((size_t)B * H * CL * 2);   // 8.4 MB
  unsigned short* ctxwT  = (unsigned short*)alloc((size_t)B * CL * H * 2);   // 8.4 MB
  unsigned short* qry_bf = (unsigned short*)alloc((size_t)B * H * QL * 2);   // 1.05 MB
  unsigned short* qryT   = (unsigned short*)alloc((size_t)B * QL * H * 2);   // 1.05 MB
  unsigned short* s1_bf  = (unsigned short*)alloc((size_t)B * CL * QL * 2);  // 16.8 MB
  unsigned short* s2u    = (unsigned short*)alloc((size_t)B * QL * CL * 2);  // 16.8 MB
  float* tpart = (float*)alloc((size_t)SPLITK5 * B * QL * H * sizeof(float)); // 16.8 MB
  unsigned short* tT_bf  = (unsigned short*)alloc((size_t)B * H * QL * 2);   // 1.05 MB
  float* pcterm = (float*)alloc((size_t)2 * B * CL * sizeof(float));
  float* pqterm = (float*)alloc((size_t)2 * B * QL * sizeof(float));
  float* cterm  = (float*)alloc((size_t)B * CL * sizeof(float));
  float* qterm  = (float*)alloc((size_t)B * QL * sizeof(float));
  float* Lpart  = (float*)alloc((size_t)B * 64 * QL * sizeof(float));        // 1 MB
  float* cinv_  = (float*)alloc((size_t)B * QL * sizeof(float));

  ktrans<CL, true><<<dim3(CL / 64, H / 64, B), dim3(256), 0, stream>>>(
      context, w + H, w + 2 * H, ctx_bf, ctxwT, pcterm);

  ktrans<QL, false><<<dim3(QL / 64, H / 64, B), dim3(256), 0, stream>>>(
      question, w, w, qry_bf, qryT, pqterm);

  kreduce<<<dim3((B * CL + B * QL + 255) / 256), dim3(256), 0, stream>>>(
      pcterm, pqterm, cterm, qterm);

  k2_fused<<<dim3(CL / 32, B), dim3(512), 0, stream>>>(
      ctxwT, qryT, cterm, qterm, c_mask, q_mask, s1_bf, s2u, Lpart);

  kLred<<<dim3((B * QL + 255) / 256), dim3(256), 0, stream>>>(Lpart, cinv_);

  k5_tpart<<<dim3(QL / 32, SPLITK5, B), dim3(256), 0, stream>>>(
      s2u, ctx_bf, tpart);

  k5b_treduce<<<dim3(QL / 64, B), dim3(256), 0, stream>>>(
      tpart, cinv_, tT_bf);

  k6_out<<<dim3(CL / 32, B), dim3(256), 0, stream>>>(
      s1_bf, qry_bf, tT_bf, context, out);
}